// Round 1
// baseline (430.227 us; speedup 1.0000x reference)
//
#include <hip/hip_runtime.h>
#include <hip/hip_bf16.h>

#define T_TOK 2048
#define DIMS  1024
#define HID   4096
#define NE    8
#define BM 128
#define BN 128
#define BK 64

typedef __bf16 bf16x8 __attribute__((ext_vector_type(8)));
typedef float  f32x4  __attribute__((ext_vector_type(4)));

__device__ __forceinline__ unsigned short f2bf(float f) {
  unsigned u = __float_as_uint(f);
  u += 0x7FFFu + ((u >> 16) & 1u);
  return (unsigned short)(u >> 16);
}
__device__ __forceinline__ float bf2f(unsigned short s) {
  return __uint_as_float(((unsigned)s) << 16);
}

__device__ __forceinline__ void g2l16(const void* g, void* l) {
  __builtin_amdgcn_global_load_lds((const __attribute__((address_space(1))) void*)g,
                                   (__attribute__((address_space(3))) void*)l,
                                   16, 0, 0);
}

// fp32 [r][c] tile (128x128) -> bf16 transposed [c][r], via swizzled LDS.
__device__ __forceinline__ void transcode_tile(const float* __restrict__ src,
    unsigned short* __restrict__ dst, int src_ld, int dst_ld, int r0, int c0,
    unsigned short* lds, int tid) {
  int rbase = tid >> 5;
  int c4l = (tid & 31) * 4;
#pragma unroll 4
  for (int it = 0; it < 16; it++) {
    int r = rbase + it * 8;
    float4 v = *(const float4*)(src + (size_t)(r0 + r) * src_ld + c0 + c4l);
    unsigned short b[4];
    b[0] = f2bf(v.x); b[1] = f2bf(v.y); b[2] = f2bf(v.z); b[3] = f2bf(v.w);
#pragma unroll
    for (int j = 0; j < 4; j++) {
      int c = c4l + j;
      int chunk = it ^ ((c >> 2) & 15);
      lds[c * 128 + chunk * 8 + rbase] = b[j];
    }
  }
  __syncthreads();
  int ck = tid & 15;
  int cb = tid >> 4;
#pragma unroll 4
  for (int it = 0; it < 8; it++) {
    int c = cb + it * 16;
    int chunk = ck ^ ((c >> 2) & 15);
    uint4 v = *(const uint4*)(&lds[c * 128 + chunk * 8]);
    *(uint4*)(dst + (size_t)(c0 + c) * dst_ld + r0 + ck * 8) = v;
  }
}

// ---------------- routing (+ fused u->bf16 cast) + W1 transcode ----------------
__global__ __launch_bounds__(256) void k_route(const float* __restrict__ u,
    const float* __restrict__ cent, const float* __restrict__ sbias,
    int* __restrict__ topk_idx, float* __restrict__ topk_val,
    unsigned short* __restrict__ ub,
    const float* __restrict__ W1, unsigned short* __restrict__ w1t) {
  __shared__ __align__(16) unsigned short tlds[128 * 128];
  if (blockIdx.x >= 512) {
    // W1 [e][k=1024][n=4096] fp32 -> w1t [e][n=4096][k=1024] bf16
    int rank = (int)blockIdx.x - 512;               // 0..2047
    int te = rank >> 8, tt = rank & 255;            // 8 k-tiles x 32 n-tiles
    int r0 = (tt & 7) * 128, c0 = (tt >> 3) * 128;
    transcode_tile(W1 + (size_t)te * DIMS * HID, w1t + (size_t)te * HID * DIMS,
                   HID, DIMS, r0, c0, tlds, threadIdx.x);
    return;
  }
  int wave = threadIdx.x >> 6;
  int lane = threadIdx.x & 63;
  int t = blockIdx.x * 4 + wave;
  const float* ur = u + (size_t)t * DIMS;
  float p[NE];
#pragma unroll
  for (int n = 0; n < NE; n++) p[n] = 0.f;
#pragma unroll
  for (int ch = 0; ch < 4; ch++) {
    int d = ch * 256 + lane * 4;
    float4 uv = *(const float4*)(ur + d);
    ushort4 o4;
    o4.x = f2bf(uv.x); o4.y = f2bf(uv.y); o4.z = f2bf(uv.z); o4.w = f2bf(uv.w);
    *(ushort4*)(ub + (size_t)t * DIMS + d) = o4;
#pragma unroll
    for (int n = 0; n < NE; n++) {
      float4 cv = *(const float4*)(cent + n * DIMS + d);
      p[n] += uv.x * cv.x + uv.y * cv.y + uv.z * cv.z + uv.w * cv.w;
    }
  }
#pragma unroll
  for (int n = 0; n < NE; n++) {
#pragma unroll
    for (int o = 32; o > 0; o >>= 1) p[n] += __shfl_xor(p[n], o);
  }
  if (lane == 0) {
    float g[NE];
    float m = -1e30f;
#pragma unroll
    for (int n = 0; n < NE; n++) { g[n] = p[n] + sbias[n]; m = fmaxf(m, g[n]); }
    float sum = 0.f;
#pragma unroll
    for (int n = 0; n < NE; n++) { g[n] = expf(g[n] - m); sum += g[n]; }
    float inv = 1.f / sum;
#pragma unroll
    for (int n = 0; n < NE; n++) g[n] *= inv;
    int i0 = 0;
#pragma unroll
    for (int n = 1; n < NE; n++) if (g[n] > g[i0]) i0 = n;
    int i1 = (i0 == 0) ? 1 : 0;
#pragma unroll
    for (int n = 0; n < NE; n++) if (n != i0 && g[n] > g[i1]) i1 = n;
    topk_idx[2 * t] = i0;     topk_idx[2 * t + 1] = i1;
    topk_val[2 * t] = g[i0];  topk_val[2 * t + 1] = g[i1];
  }
}

// counts + offsets + maxvio + placement, one block
__global__ __launch_bounds__(256) void k_finalize(const int* __restrict__ topk_idx,
    int* __restrict__ cnt, int* __restrict__ offs, float* __restrict__ maxvio,
    int* __restrict__ rowtok, int* __restrict__ pairpos) {
  __shared__ int lc[NE], lcur[NE];
  int tid = threadIdx.x;
  if (tid < NE) lc[tid] = 0;
  __syncthreads();
#pragma unroll
  for (int i = 0; i < 16; i++) {
    int e = topk_idx[tid * 16 + i];
    atomicAdd(&lc[e], 1);
  }
  __syncthreads();
  if (tid == 0) {
    int o = 0, mx = 0;
#pragma unroll
    for (int n = 0; n < NE; n++) {
      int c = lc[n];
      cnt[n] = c; offs[n] = o; lcur[n] = o;
      o += c; mx = max(mx, c);
    }
    maxvio[0] = ((float)mx - 512.f) / 512.f;
  }
  __syncthreads();
#pragma unroll
  for (int i = 0; i < 8; i++) {
    int t = tid + i * 256;
#pragma unroll
    for (int k = 0; k < 2; k++) {
      int e = topk_idx[2 * t + k];
      int pos = atomicAdd(&lcur[e], 1);
      rowtok[pos] = t;
      pairpos[2 * t + k] = pos;
    }
  }
}

// ---------------- GEMM1 NEW: pure bf16 dbuf pipeline (+ W2 transpose in idle) --
__global__ __launch_bounds__(256) void k_gemm1n(const unsigned short* __restrict__ ub,
    const unsigned short* __restrict__ w1t, const float* __restrict__ b1,
    const int* __restrict__ rowtok, const int* __restrict__ cnts, const int* __restrict__ offs,
    unsigned short* __restrict__ h,
    const float* __restrict__ W2, unsigned short* __restrict__ w2t) {
  __shared__ __align__(16) unsigned char smem[65536];
  int tid = threadIdx.x;
  int e = blockIdx.z;
  int cnt = cnts[e];
  int m0 = blockIdx.y * BM;

  if (m0 >= cnt) {
    // ---- W2 transpose worker ----
    int live[NE];
#pragma unroll
    for (int z = 0; z < NE; z++) live[z] = min(16, (cnts[z] + BM - 1) >> 7);
    int rank = 0;
    for (int z = 0; z < e; z++) rank += (16 - live[z]) * 32;
    rank += ((int)blockIdx.y - live[e]) * 32 + (int)blockIdx.x;
    if (rank >= 2048) return;
    int te = rank >> 8, tt = rank & 255;
    transcode_tile(W2 + (size_t)te * HID * DIMS, w2t + (size_t)te * HID * DIMS,
                   DIMS, HID, (tt & 31) * 128, (tt >> 5) * 128,
                   (unsigned short*)smem, tid);
    return;
  }

  // ---- GEMM compute path (double-buffered, counted vmcnt) ----
  int off = offs[e];
  int n0 = blockIdx.x * BN;
  int lane = tid & 63;
  int wm = (tid >> 7) & 1;
  int wn = (tid >> 6) & 1;
  int srow = tid >> 3;
  int cp = tid & 7;
  const unsigned short* gA[4];
  const unsigned short* gB[4];
#pragma unroll
  for (int a = 0; a < 4; a++) {
    int r = a * 32 + srow;
    int c = cp ^ (r & 7);
    int pr = min(off + m0 + r, off + cnt - 1);
    int tok = rowtok[pr];
    gA[a] = ub + (size_t)tok * DIMS + c * 8;
    gB[a] = w1t + ((size_t)e * HID + (n0 + r)) * DIMS + c * 8;
  }
  unsigned wboff = (unsigned)__builtin_amdgcn_readfirstlane((tid >> 6) << 10);
  f32x4 acc[4][4];
  f32x4 zz = {0.f, 0.f, 0.f, 0.f};
#pragma unroll
  for (int i = 0; i < 4; i++)
#pragma unroll
    for (int j = 0; j < 4; j++) acc[i][j] = zz;

  int lane15 = lane & 15, quad = lane >> 4, l7 = lane & 7;
  unsigned aOff = (unsigned)((wm * 64 + lane15) * 128);
  unsigned bOff = (unsigned)(16384 + (wn * 64 + lane15) * 128);

  // prologue: stage tile 0 into buffer 0
#pragma unroll
  for (int a = 0; a < 4; a++) g2l16(gA[a], smem + a * 4096 + wboff);
#pragma unroll
  for (int a = 0; a < 4; a++) g2l16(gB[a], smem + 16384 + a * 4096 + wboff);

#pragma unroll 1
  for (int it = 0; it < DIMS / BK; it++) {
    unsigned base = (unsigned)((it & 1) << 15);
    unsigned nb = base ^ 32768u;
    if (it + 1 < DIMS / BK) {
      int k1 = (it + 1) * BK;
#pragma unroll
      for (int a = 0; a < 4; a++) g2l16(gA[a] + k1, smem + nb + a * 4096 + wboff);
#pragma unroll
      for (int a = 0; a < 4; a++) g2l16(gB[a] + k1, smem + nb + 16384 + a * 4096 + wboff);
      asm volatile("s_waitcnt vmcnt(8)" ::: "memory");   // current tile's 8 loads done
    } else {
      asm volatile("s_waitcnt vmcnt(0)" ::: "memory");
    }
    __builtin_amdgcn_s_barrier();
    __builtin_amdgcn_sched_barrier(0);
#pragma unroll
    for (int s = 0; s < 2; s++) {
      unsigned cpf = (unsigned)(((s * 4 + quad) ^ l7) * 16);
      bf16x8 af[4], bfr[4];
#pragma unroll
      for (int i = 0; i < 4; i++) af[i] = *(const bf16x8*)(smem + base + aOff + i * 2048 + cpf);
#pragma unroll
      for (int j = 0; j < 4; j++) bfr[j] = *(const bf16x8*)(smem + base + bOff + j * 2048 + cpf);
#pragma unroll
      for (int i = 0; i < 4; i++)
#pragma unroll
        for (int j = 0; j < 4; j++)
          acc[i][j] = __builtin_amdgcn_mfma_f32_16x16x32_bf16(af[i], bfr[j], acc[i][j], 0, 0, 0);
    }
    __builtin_amdgcn_sched_barrier(0);
    asm volatile("s_waitcnt lgkmcnt(0)" ::: "memory");   // my ds_reads of this buffer done
    __builtin_amdgcn_s_barrier();                        // safe to overwrite next iter
  }
  float b1v[4];
#pragma unroll
  for (int j = 0; j < 4; j++) b1v[j] = b1[e * HID + n0 + wn * 64 + j * 16 + lane15];
#pragma unroll
  for (int i = 0; i < 4; i++) {
#pragma unroll
    for (int r = 0; r < 4; r++) {
      int mrow = m0 + wm * 64 + i * 16 + quad * 4 + r;
      if (mrow < cnt) {
        size_t hrow = (size_t)(off + mrow) * HID;
#pragma unroll
        for (int j = 0; j < 4; j++) {
          int col = n0 + wn * 64 + j * 16 + lane15;
          float v = fmaxf(acc[i][j][r] + b1v[j], 0.f);
          h[hrow + col] = f2bf(v);
        }
      }
    }
  }
}

// ---------------- GEMM1 LEGACY (fallback when ws too small for w1t) ----------
__global__ __launch_bounds__(256) void k_gemm1o(const unsigned short* __restrict__ ub,
    const float* __restrict__ W1, const float* __restrict__ b1,
    const int* __restrict__ rowtok, const int* __restrict__ cnts, const int* __restrict__ offs,
    unsigned short* __restrict__ h,
    const float* __restrict__ W2, unsigned short* __restrict__ w2t) {
  __shared__ __align__(16) unsigned char smem[32768];
  int tid = threadIdx.x;
  int e = blockIdx.z;
  int cnt = cnts[e];
  int m0 = blockIdx.y * BM;

  if (m0 >= cnt) {
    int live[NE];
#pragma unroll
    for (int z = 0; z < NE; z++) live[z] = min(16, (cnts[z] + BM - 1) >> 7);
    int rank = 0;
    for (int z = 0; z < e; z++) rank += (16 - live[z]) * 32;
    rank += ((int)blockIdx.y - live[e]) * 32 + (int)blockIdx.x;
    if (rank >= 2048) return;
    int te = rank >> 8, tt = rank & 255;
    transcode_tile(W2 + (size_t)te * HID * DIMS, w2t + (size_t)te * HID * DIMS,
                   DIMS, HID, (tt & 31) * 128, (tt >> 5) * 128,
                   (unsigned short*)smem, tid);
    return;
  }

  int off = offs[e];
  int n0 = blockIdx.x * BN;
  int lane = tid & 63;
  int wv = tid >> 6;
  int wm = (tid >> 7) & 1;
  int wn = (tid >> 6) & 1;
  int srow = tid >> 3;
  int cp = tid & 7;
  const float* w1e = W1 + (size_t)e * DIMS * HID;
  const unsigned short* gAp[4];
#pragma unroll
  for (int a = 0; a < 4; a++) {
    int r = a * 32 + srow;
    int c = cp ^ (r & 7);
    int pr = min(off + m0 + r, off + cnt - 1);
    int tok = rowtok[pr];
    gAp[a] = ub + (size_t)tok * DIMS + c * 8;
  }
  int wboff = __builtin_amdgcn_readfirstlane(wv << 10);
  f32x4 acc[4][4];
  f32x4 zz = {0.f, 0.f, 0.f, 0.f};
#pragma unroll
  for (int i = 0; i < 4; i++)
#pragma unroll
    for (int j = 0; j < 4; j++) acc[i][j] = zz;

  int lane15 = lane & 15, quad = lane >> 4, l7 = lane & 7;
  unsigned aRowOff = (unsigned)((wm * 64 + lane15) * 128);
  unsigned bRowOff = (unsigned)(16384 + (wn * 64 + lane15) * 128);

#pragma unroll 1
  for (int k0 = 0; k0 < DIMS; k0 += BK) {
#pragma unroll
    for (int a = 0; a < 4; a++) g2l16(gAp[a] + k0, smem + a * 4096 + wboff);
#pragma unroll
    for (int jj = 0; jj < 4; jj++) {
      int j = wv * 4 + jj;
      int kc = j & 7, nh = j >> 3;
      int nloc = nh * 64 + lane;
      const float* src = w1e + (size_t)(k0 + kc * 8) * HID + n0 + nloc;
      float t0, t1, t2, t3, t4, t5, t6, t7;
      t0 = src[0];            t1 = src[(size_t)HID];
      t2 = src[(size_t)2 * HID]; t3 = src[(size_t)3 * HID];
      t4 = src[(size_t)4 * HID]; t5 = src[(size_t)5 * HID];
      t6 = src[(size_t)6 * HID]; t7 = src[(size_t)7 * HID];
      bf16x8 pk;
      pk[0] = (__bf16)t0; pk[1] = (__bf16)t1; pk[2] = (__bf16)t2; pk[3] = (__bf16)t3;
      pk[4] = (__bf16)t4; pk[5] = (__bf16)t5; pk[6] = (__bf16)t6; pk[7] = (__bf16)t7;
      int cs = kc ^ (lane & 7);
      *(bf16x8*)(smem + 16384 + nloc * 128 + cs * 16) = pk;
    }
    __syncthreads();
#pragma unroll
    for (int s = 0; s < 2; s++) {
      unsigned cpf = (unsigned)(((s * 4 + quad) ^ l7) * 16);
      bf16x8 af[4], bfr[4];
#pragma unroll
      for (int i = 0; i < 4; i++) af[i] = *(const bf16x8*)(smem + aRowOff + i * 2048 + cpf);
#pragma unroll
      for (int j = 0; j < 4; j++) bfr[j] = *(const bf16x8*)(smem + bRowOff + j * 2048 + cpf);
#pragma unroll
      for (int i = 0; i < 4; i++)
#pragma unroll
        for (int j = 0; j < 4; j++)
          acc[i][j] = __builtin_amdgcn_mfma_f32_16x16x32_bf16(af[i], bfr[j], acc[i][j], 0, 0, 0);
    }
    __syncthreads();
  }
  float b1v[4];
#pragma unroll
  for (int j = 0; j < 4; j++) b1v[j] = b1[e * HID + n0 + wn * 64 + j * 16 + lane15];
#pragma unroll
  for (int i = 0; i < 4; i++) {
#pragma unroll
    for (int r = 0; r < 4; r++) {
      int mrow = m0 + wm * 64 + i * 16 + quad * 4 + r;
      if (mrow < cnt) {
        size_t hrow = (size_t)(off + mrow) * HID;
#pragma unroll
        for (int j = 0; j < 4; j++) {
          int col = n0 + wn * 64 + j * 16 + lane15;
          float v = fmaxf(acc[i][j][r] + b1v[j], 0.f);
          h[hrow + col] = f2bf(v);
        }
      }
    }
  }
}

// ---------------- GEMM2: dbuf pipeline from pre-transposed w2t ---------------
__global__ __launch_bounds__(256) void k_gemm2(const unsigned short* __restrict__ hbuf,
    const unsigned short* __restrict__ w2t, const float* __restrict__ b2,
    const int* __restrict__ cnts, const int* __restrict__ offs,
    unsigned short* __restrict__ pout, int KC) {
  int z = blockIdx.z;
  int e = z & 7;
  int sp = z >> 3;
  int cnt = cnts[e];
  int m0 = blockIdx.y * BM;
  if (m0 >= cnt) return;
  int off = offs[e];
  int n0 = blockIdx.x * BN;
  __shared__ __align__(16) unsigned char smem[65536];

  int tid = threadIdx.x;
  int lane = tid & 63;
  int wm = (tid >> 7) & 1;
  int wn = (tid >> 6) & 1;
  int srow = tid >> 3;
  int cp = tid & 7;
  const unsigned short* gA[4];
  const unsigned short* gB[4];
#pragma unroll
  for (int a = 0; a < 4; a++) {
    int r = a * 32 + srow;
    int c = cp ^ (r & 7);
    int pr = min(off + m0 + r, off + cnt - 1);
    gA[a] = hbuf + (size_t)pr * HID + c * 8;
    gB[a] = w2t + ((size_t)e * DIMS + (n0 + r)) * HID + c * 8;
  }
  unsigned wboff = (unsigned)__builtin_amdgcn_readfirstlane((tid >> 6) << 10);
  f32x4 acc[4][4];
  f32x4 zz = {0.f, 0.f, 0.f, 0.f};
#pragma unroll
  for (int i = 0; i < 4; i++)
#pragma unroll
    for (int j = 0; j < 4; j++) acc[i][j] = zz;

  int lane15 = lane & 15, quad = lane >> 4, l7 = lane & 7;
  unsigned aOff = (unsigned)((wm * 64 + lane15) * 128);
  unsigned bOff = (unsigned)(16384 + (wn * 64 + lane15) * 128);

  int kbeg = sp * KC;
  int NIT = KC / BK;
  // prologue
#pragma unroll
  for (int a = 0; a < 4; a++) g2l16(gA[a] + kbeg, smem + a * 4096 + wboff);
#pragma unroll
  for (int a = 0; a < 4; a++) g2l16(gB[a] + kbeg, smem + 16384 + a * 4096 + wboff);

#pragma unroll 1
  for (int it = 0; it < NIT; it++) {
    unsigned base = (unsigned)((it & 1) << 15);
    unsigned nb = base ^ 32768u;
    if (it + 1 < NIT) {
      int k1 = kbeg + (it + 1) * BK;
#pragma unroll
      for (int a = 0; a < 4; a++) g2l16(gA[a] + k1, smem + nb + a * 4096 + wboff);
#pragma unroll
      for (int a = 0; a < 4; a++) g2l16(gB[a] + k1, smem + nb + 16384 + a * 4096 + wboff);
      asm volatile("s_waitcnt vmcnt(8)" ::: "memory");
    } else {
      asm volatile("s_waitcnt vmcnt(0)" ::: "memory");
    }
    __builtin_amdgcn_s_barrier();
    __builtin_amdgcn_sched_barrier(0);
#pragma unroll
    for (int s = 0; s < 2; s++) {
      unsigned cpf = (unsigned)(((s * 4 + quad) ^ l7) * 16);
      bf16x8 af[4], bfr[4];
#pragma unroll
      for (int i = 0; i < 4; i++) af[i] = *(const bf16x8*)(smem + base + aOff + i * 2048 + cpf);
#pragma unroll
      for (int j = 0; j < 4; j++) bfr[j] = *(const bf16x8*)(smem + base + bOff + j * 2048 + cpf);
#pragma unroll
      for (int i = 0; i < 4; i++)
#pragma unroll
        for (int j = 0; j < 4; j++)
          acc[i][j] = __builtin_amdgcn_mfma_f32_16x16x32_bf16(af[i], bfr[j], acc[i][j], 0, 0, 0);
    }
    __builtin_amdgcn_sched_barrier(0);
    asm volatile("s_waitcnt lgkmcnt(0)" ::: "memory");
    __builtin_amdgcn_s_barrier();
  }
  float b2v[4];
#pragma unroll
  for (int j = 0; j < 4; j++)
    b2v[j] = (sp == 0) ? b2[e * DIMS + n0 + wn * 64 + j * 16 + lane15] : 0.f;
  unsigned short* pme = pout + (size_t)sp * T_TOK * 2 * DIMS;
#pragma unroll
  for (int i = 0; i < 4; i++) {
#pragma unroll
    for (int r = 0; r < 4; r++) {
      int mrow = m0 + wm * 64 + i * 16 + quad * 4 + r;
      if (mrow < cnt) {
        size_t prow = (size_t)(off + mrow) * DIMS;
#pragma unroll
        for (int j = 0; j < 4; j++) {
          int col = n0 + wn * 64 + j * 16 + lane15;
          pme[prow + col] = f2bf(acc[i][j][r] + b2v[j]);
        }
      }
    }
  }
}

// ---------------- combine (bf16 partials) ----------------
__global__ __launch_bounds__(256) void k_combine(const unsigned short* __restrict__ pout,
    const int* __restrict__ pairpos, const float* __restrict__ tkv,
    float* __restrict__ out, int nsplit) {
  int t = blockIdx.x;
  int d = threadIdx.x * 4;
  int p0 = pairpos[2 * t], p1 = pairpos[2 * t + 1];
  float w0 = tkv[2 * t], w1 = tkv[2 * t + 1];
  float a0 = 0.f, a1 = 0.f, a2 = 0.f, a3 = 0.f;
  float c0 = 0.f, c1 = 0.f, c2 = 0.f, c3 = 0.f;
  const size_t SS = (size_t)T_TOK * 2 * DIMS;
  for (int s = 0; s < nsplit; s++) {
    ushort4 av = *(const ushort4*)(pout + s * SS + (size_t)p0 * DIMS + d);
    ushort4 bv = *(const ushort4*)(pout + s * SS + (size_t)p1 * DIMS + d);
    a0 += bf2f(av.x); a1 += bf2f(av.y); a2 += bf2f(av.z); a3 += bf2f(av.w);
    c0 += bf2f(bv.x); c1 += bf2f(bv.y); c2 += bf2f(bv.z); c3 += bf2f(bv.w);
  }
  float4 o;
  o.x = w0 * a0 + w1 * c0;
  o.y = w0 * a1 + w1 * c1;
  o.z = w0 * a2 + w1 * c2;
  o.w = w0 * a3 + w1 * c3;
  *(float4*)(out + (size_t)t * DIMS + d) = o;
}

extern "C" void kernel_launch(void* const* d_in, const int* in_sizes, int n_in,
                              void* d_out, int out_size, void* d_ws, size_t ws_size,
                              hipStream_t stream) {
  const float* u     = (const float*)d_in[0];
  const float* cent  = (const float*)d_in[1];
  const float* sbias = (const float*)d_in[2];
  const float* W1    = (const float*)d_in[3];
  const float* b1    = (const float*)d_in[4];
  const float* W2    = (const float*)d_in[5];
  const float* b2    = (const float*)d_in[6];
  float* out = (float*)d_out;

  char* ws = (char*)d_ws;
  unsigned short* ubuf = (unsigned short*)(ws);                 //  4 MB
  unsigned short* hbuf = (unsigned short*)(ws + 4194304);       // 32 MB
  unsigned short* w2t  = (unsigned short*)(ws + 37748736);      // 64 MB
  const size_t REG4 = 104857600ull;                             // 100 MB mark
  const size_t PSZ = (size_t)T_TOK * 2 * DIMS * 2;              // 8 MB per split
  const size_t NEED_NEW = REG4 + 67108864ull + 1048576ull;      // w1t + small bufs

  if (ws_size >= NEED_NEW) {
    // new layout: w1t at 100MB (64MB); pout aliases w1t (w1t dead after gemm1)
    unsigned short* w1t   = (unsigned short*)(ws + REG4);
    unsigned short* poutb = (unsigned short*)(ws + REG4);
    const int nsplit = 2;
    char* r = ws + REG4 + 67108864ull;
    int*   cnt      = (int*)(r);
    int*   offs     = (int*)(r + 64);
    int*   topk_idx = (int*)(r + 256);
    float* topk_val = (float*)(r + 256 + 16384);
    int*   rowtok   = (int*)(r + 256 + 32768);
    int*   pairpos  = (int*)(r + 256 + 49152);

    k_route<<<2560, 256, 0, stream>>>(u, cent, sbias, topk_idx, topk_val, ubuf, W1, w1t);
    k_finalize<<<1, 256, 0, stream>>>(topk_idx, cnt, offs, out + 2097152, rowtok, pairpos);
    k_gemm1n<<<dim3(32, 16, 8), 256, 0, stream>>>(ubuf, w1t, b1, rowtok, cnt, offs, hbuf,
                                                  W2, w2t);
    k_gemm2<<<dim3(8, 16, 8 * nsplit), 256, 0, stream>>>(hbuf, w2t, b2, cnt, offs,
                                                         poutb, HID / nsplit);
    k_combine<<<2048, 256, 0, stream>>>(poutb, pairpos, topk_val, out, nsplit);
  } else {
    // legacy layout/path
    int nsplit = (ws_size >= REG4 + 4 * PSZ + (1u << 20)) ? 4 : 1;
    unsigned short* poutb = (unsigned short*)(ws + REG4);
    char* r = ws + REG4 + (size_t)nsplit * PSZ;
    int*   cnt      = (int*)(r);
    int*   offs     = (int*)(r + 64);
    int*   topk_idx = (int*)(r + 256);
    float* topk_val = (float*)(r + 256 + 16384);
    int*   rowtok   = (int*)(r + 256 + 32768);
    int*   pairpos  = (int*)(r + 256 + 49152);

    k_route<<<512, 256, 0, stream>>>(u, cent, sbias, topk_idx, topk_val, ubuf, W1, ubuf);
    k_finalize<<<1, 256, 0, stream>>>(topk_idx, cnt, offs, out + 2097152, rowtok, pairpos);
    k_gemm1o<<<dim3(32, 16, 8), 256, 0, stream>>>(ubuf, W1, b1, rowtok, cnt, offs, hbuf,
                                                  W2, w2t);
    k_gemm2<<<dim3(8, 16, 8 * nsplit), 256, 0, stream>>>(hbuf, w2t, b2, cnt, offs,
                                                         poutb, HID / nsplit);
    k_combine<<<2048, 256, 0, stream>>>(poutb, pairpos, topk_val, out, nsplit);
  }
}